// Round 16
// baseline (180.977 us; speedup 1.0000x reference)
//
#include <hip/hip_runtime.h>
#include <hip/hip_bf16.h>
#include <math.h>

#define TT 256          // T
#define EE 128          // E
#define TJ 16           // j-tile
#define VTB 12288       // bytes per staged velocity tile (16 j x 384 bf16)

typedef __attribute__((ext_vector_type(8))) short short8v;
typedef __attribute__((ext_vector_type(4))) float f32x4;

__device__ __forceinline__ float silu_f(float x) {
    return x * __builtin_amdgcn_rcpf(1.0f + __expf(-x));
}

__device__ __forceinline__ unsigned short f2bf(float f) {
    union { float f; unsigned u; } x; x.f = f;
    unsigned r = (x.u + 0x7FFFu + ((x.u >> 16) & 1u)) >> 16;
    return (unsigned short)r;
}

__device__ __forceinline__ unsigned cvt_pk_bf16(float lo, float hi) {
    unsigned r;
    asm("v_cvt_pk_bf16_f32 %0, %1, %2" : "=v"(r) : "v"(lo), "v"(hi));
    return r;
}

__device__ __forceinline__ float bflo(unsigned u) { return __uint_as_float(u << 16); }
__device__ __forceinline__ float bfhi(unsigned u) { return __uint_as_float(u & 0xffff0000u); }
__device__ __forceinline__ float bfu(unsigned short u) { return __uint_as_float(((unsigned)u) << 16); }

// ---------------- packW: pre-pack MFMA B-fragments (bf16, fragment order) ----------------
__global__ __launch_bounds__(256) void packW_kernel(
    const float* __restrict__ Wdk, const float* __restrict__ Wdv,
    unsigned short* __restrict__ wfrag) {
    const int idx = blockIdx.x * 256 + threadIdx.x;   // 0..4095
    const int lane = idx & 63;
    const int kh = (idx >> 6) & 1;
    const int nn = (idx >> 7) & 7;
    const int w = idx >> 10;                          // 0..3
    const float* Wsel; int wstride, colbase;
    if (w == 0) { Wsel = Wdk; wstride = 128; colbase = 0; }
    else { Wsel = Wdv; wstride = 384; colbase = (w - 1) * 128; }
    const int lrow = lane >> 4;
    const int lcol = lane & 15;
    const int col = colbase + nn * 16 + lcol;
    unsigned short* dst = wfrag + (size_t)idx * 8;
#pragma unroll
    for (int e = 0; e < 8; ++e) {
        const int k = kh * 32 + lrow * 8 + e;
        dst[e] = f2bf(Wsel[k * wstride + col]);
    }
}

// ---------------- Phase A: projections + bf16 velocity packing ----------------
__global__ __launch_bounds__(256) void phaseA_kernel(
    const float* __restrict__ query, const float* __restrict__ velocity,
    const float* __restrict__ Wq, const float* __restrict__ bq,
    const float* __restrict__ Wk, const float* __restrict__ bk,
    const float* __restrict__ Wv, const float* __restrict__ bv,
    const float* __restrict__ Wvel, const float* __restrict__ bvel,
    float* __restrict__ qs_ws, float* __restrict__ kk_ws,
    float* __restrict__ vproj_ws, unsigned short* __restrict__ velb16,
    float* __restrict__ veldot_ws, float* __restrict__ w3_ws) {
    const int row = blockIdx.x;           // b*T + i
    const int t = threadIdx.x;
    __shared__ float sIn[EE];
    __shared__ float sVel[3 * EE];
    __shared__ float sVelp[3 * 384];
    if (t < EE) sIn[t] = query[(size_t)row * EE + t];
    for (int idx = t; idx < 3 * EE; idx += 256)
        sVel[idx] = velocity[(size_t)row * 3 * EE + idx];
    __syncthreads();

    for (int o = t; o < 640; o += 256) {
        if (o < 128) {
            int c = o;
            float acc = bq[c];
#pragma unroll 8
            for (int r = 0; r < 128; ++r) acc = fmaf(sIn[r], Wq[r * 128 + c], acc);
            qs_ws[(size_t)row * 128 + c] = acc * 0.25f;   // * d^-0.5
        } else if (o < 256) {
            int c = o - 128;
            float acc = bk[c];
#pragma unroll 8
            for (int r = 0; r < 128; ++r) acc = fmaf(sIn[r], Wk[r * 128 + c], acc);
            kk_ws[(size_t)row * 128 + c] = acc;
        } else {
            int c = o - 256;
            float acc = bv[c];
#pragma unroll 8
            for (int r = 0; r < 128; ++r) acc = fmaf(sIn[r], Wv[r * 384 + c], acc);
            vproj_ws[(size_t)row * 384 + c] = acc;
        }
    }
    // bf16 velocity pack (contiguous [row][384])
    for (int idx = t; idx < 384; idx += 256)
        velb16[(size_t)row * 384 + idx] = f2bf(sVel[idx]);

    for (int c = t; c < 384; c += 256) {
        float a0 = bvel[c], a1 = a0, a2 = a0;
#pragma unroll 8
        for (int r = 0; r < 128; ++r) {
            float w = Wvel[r * 384 + c];
            a0 = fmaf(sVel[r], w, a0);
            a1 = fmaf(sVel[128 + r], w, a1);
            a2 = fmaf(sVel[256 + r], w, a2);
        }
        sVelp[0 * 384 + c] = a0;
        sVelp[1 * 384 + c] = a1;
        sVelp[2 * 384 + c] = a2;
    }
    __syncthreads();
    if (t < 128) {
        int c = t;
        float vd = 0.f;
#pragma unroll
        for (int s = 0; s < 3; ++s)
            vd += sVelp[s * 384 + c] * sVelp[s * 384 + 128 + c];
        veldot_ws[(size_t)row * 128 + c] = vd;
#pragma unroll
        for (int s = 0; s < 3; ++s)
            w3_ws[((size_t)row * 3 + s) * 128 + c] = sVelp[s * 384 + 256 + c];
    }
}

// ---------------- Phase B: MFMA edge MLP + elementwise attention ----------------
// Velocity tiles async-staged (dbuf, global_load_lds); gates hoisted from L2.
__global__ __launch_bounds__(256, 3) void phaseB_kernel(
    const float* __restrict__ edge_feature, const float* __restrict__ edge_direction,
    const float* __restrict__ cutoff, const unsigned short* __restrict__ velb16,
    const unsigned short* __restrict__ wfrag,
    const float* __restrict__ bdk, const float* __restrict__ bdv,
    const float* __restrict__ qs_ws, const float* __restrict__ kk_ws,
    const float* __restrict__ vproj_ws,
    float* __restrict__ attn_ws, float* __restrict__ vec_ws) {
    // XCD swizzle: xcd = blk%8; each XCD serves one batch-half's L2 reuse set.
    const int blk = blockIdx.x;
    const int x = blk & 7;
    const int slot = blk >> 3;            // 0..127
    const int b = x >> 1;
    const int i = ((x & 1) << 7) + slot;
    const int row = b * TT + i;

    const int t = threadIdx.x;
    const int wave = t >> 6;
    const int lane = t & 63;
    const int lrow = lane >> 4;            // 0..3
    const int lcol = lane & 15;            // 0..15

    __shared__ __align__(16) unsigned char sVelS[2 * VTB];   // staged bf16 vel tiles, dbuf
    __shared__ __align__(16) unsigned char sEFb[16 * 128];   // bf16 EF tile, XOR-swizzled
    __shared__ unsigned short sKD[128 * 18];                 // kk*silu(dk), [c][j]
    __shared__ unsigned short sGV[3 * 128 * 18];             // vproj*silu(dv), [plane][c][j]
    __shared__ float sCut[TJ];
    __shared__ float sDirS[TJ * 3];
    __shared__ float sMrg[128][5];

    // Per-wave column ownership; weights from wfrag (fragment-ordered).
    const float* Bsel;
    int colbase;
    if (wave == 0) { Bsel = bdk; colbase = 0; }
    else { Bsel = bdv; colbase = (wave - 1) * 128; }

    float biasv[8];
#pragma unroll
    for (int n = 0; n < 8; ++n)
        biasv[n] = Bsel[colbase + n * 16 + lcol];

    const unsigned short* wfbase = wfrag + ((size_t)wave * 1024 + lane) * 8;

    // gate-source array (f32, L2-resident per XCD)
    const float* gsrc = (wave == 0) ? (kk_ws + (size_t)(b * TT) * 128)
                                    : (vproj_ws + (size_t)(b * TT) * 384);
    const int gstride = (wave == 0) ? 128 : 384;

    const int grp = t >> 7;        // j-half for attention phase
    const int c = t & 127;         // channel
    const float qsc = qs_ws[(size_t)row * 128 + c] * 0.25f;   // extra /sqrt(d)

    float l = 0.f, A = 0.f;
    float v0 = 0.f, v1 = 0.f, v2 = 0.f;

    const size_t ef_base = (size_t)row * TT * 64;
    const size_t cut_base = (size_t)row * TT;
    const size_t dir_base = (size_t)row * TT * 3;
    const unsigned char* velbB = (const unsigned char*)(velb16 + (size_t)(b * TT) * 384);

    const int ldsoff = (t & 192) * 16;    // wave*1024, wave-uniform

    // ---- prologue: async-stage vel tile 0 into buf 0 ----
#pragma unroll
    for (int r = 0; r < 3; ++r)
        __builtin_amdgcn_global_load_lds(
            (const void*)(velbB + (size_t)r * 4096 + (size_t)t * 16),
            (void*)(sVelS + r * 4096 + ldsoff), 16, 0, 0);

    f32x4 pEf = ((const f32x4*)(edge_feature + ef_base))[t];
    float pCut = (t < TJ) ? cutoff[cut_base + t] : 0.f;
    float pDir = (t < TJ * 3) ? edge_direction[dir_base + t] : 0.f;

    int p = 0;
    for (int j0 = 0; j0 < TT; j0 += TJ) {
        {   // write staged EF tile (bf16, XOR swizzle)
            const int erow = t >> 4;
            const int kq = t & 15;
            unsigned plo = cvt_pk_bf16(pEf[0], pEf[1]);
            unsigned phi = cvt_pk_bf16(pEf[2], pEf[3]);
            const int byteoff = (kq * 8) ^ ((erow & 7) << 4);
            *(int2*)(sEFb + erow * 128 + byteoff) = make_int2((int)plo, (int)phi);
            if (t < TJ) sCut[t] = pCut;
            if (t < TJ * 3) sDirS[t] = pDir;
        }
        __syncthreads();   // drains vel stage -> buf[p] ready; EF tile ready

        // ---- issue async vel stage for next tile into buf[p^1] ----
        if (j0 + TJ < TT) {
            const unsigned char* src = velbB + (size_t)(j0 + TJ) * 768;
            unsigned char* dst = sVelS + (p ^ 1) * VTB;
#pragma unroll
            for (int r = 0; r < 3; ++r)
                __builtin_amdgcn_global_load_lds(
                    (const void*)(src + (size_t)r * 4096 + (size_t)t * 16),
                    (void*)(dst + r * 4096 + ldsoff), 16, 0, 0);
        }
        // reg-prefetch next EF/cut/dir (wrap; consumed after next barrier)
        {
            const int jn = (j0 + TJ) & 255;
            pEf = ((const f32x4*)(edge_feature + ef_base + (size_t)jn * 64))[t];
            pCut = (t < TJ) ? cutoff[cut_base + jn + t] : 0.f;
            pDir = (t < TJ * 3) ? edge_direction[dir_base + (size_t)jn * 3 + t] : 0.f;
        }

        // ---- MFMA: [16 j x 64 R] @ [64 x 512] -> silu -> gate product -> LDS ----
        {
            const int arow = lcol;
            const int swzb = (arow & 7) << 4;
            const short8v a0 = *(const short8v*)(sEFb + arow * 128 + ((lrow * 16) ^ swzb));
            const short8v a1 = *(const short8v*)(sEFb + arow * 128 + ((64 + lrow * 16) ^ swzb));
            const int jb = j0 + lrow * 4;

            // hoist all 32 gate loads: independent, issue together, one wait
            float gg[8][4];
#pragma unroll
            for (int n = 0; n < 8; ++n) {
                const float* gp = gsrc + (size_t)jb * gstride + colbase + n * 16 + lcol;
                gg[n][0] = gp[0];
                gg[n][1] = gp[gstride];
                gg[n][2] = gp[2 * gstride];
                gg[n][3] = gp[3 * gstride];
            }
#pragma unroll
            for (int n = 0; n < 8; ++n) {
                const int col = colbase + n * 16 + lcol;
                const short8v b0 = *(const short8v*)(wfbase + (size_t)n * 1024);
                const short8v b1 = *(const short8v*)(wfbase + (size_t)n * 1024 + 512);
                f32x4 acc = {biasv[n], biasv[n], biasv[n], biasv[n]};
                acc = __builtin_amdgcn_mfma_f32_16x16x32_bf16(a0, b0, acc, 0, 0, 0);
                acc = __builtin_amdgcn_mfma_f32_16x16x32_bf16(a1, b1, acc, 0, 0, 0);
                const float r0 = gg[n][0] * silu_f(acc[0]);
                const float r1 = gg[n][1] * silu_f(acc[1]);
                const float r2 = gg[n][2] * silu_f(acc[2]);
                const float r3 = gg[n][3] * silu_f(acc[3]);
                const unsigned w01 = cvt_pk_bf16(r0, r1);
                const unsigned w23 = cvt_pk_bf16(r2, r3);
                unsigned short* dst;
                if (wave == 0) {
                    dst = &sKD[col * 18 + lrow * 4];
                } else {
                    const int plane = (col >> 4) % 3;
                    const int cch = (col / 48) * 16 + lcol;
                    dst = &sGV[plane * 2304 + cch * 18 + lrow * 4];
                }
                *(unsigned*)(dst) = w01;
                *(unsigned*)(dst + 2) = w23;
            }
        }
        __syncthreads();   // drains next-tile vel stage; sKD/sGV visible

        // ---- attention accumulation: 2 j-groups x 128 channels ----
        {
            const unsigned short* srow = (const unsigned short*)(sVelS + p * VTB);
            const int jlo = grp * (TJ / 2);
#pragma unroll
            for (int q = 0; q < 4; ++q) {
                const int jj = jlo + 2 * q;
                const unsigned kd2 = *(const unsigned*)(&sKD[c * 18 + jj]);
                const unsigned vg2 = *(const unsigned*)(&sGV[0 * 2304 + c * 18 + jj]);
                const unsigned p12 = *(const unsigned*)(&sGV[1 * 2304 + c * 18 + jj]);
                const unsigned p22 = *(const unsigned*)(&sGV[2 * 2304 + c * 18 + jj]);
                const float cut0 = sCut[jj];
                const float cut1 = sCut[jj + 1];
                const float p0 = __expf(qsc * bflo(kd2));
                const float p1 = __expf(qsc * bfhi(kd2));
                l += p0 + p1;
                A = fmaf(p0 * cut0, bflo(vg2), A);
                A = fmaf(p1 * cut1, bfhi(vg2), A);
                if (cut0 != 0.0f) {
                    const unsigned short* vp = srow + (size_t)jj * 384 + c;
                    const float w1 = bflo(p12), w2 = bflo(p22);
                    v0 = fmaf(bfu(vp[0]),   w1, fmaf(w2, sDirS[jj * 3 + 0], v0));
                    v1 = fmaf(bfu(vp[128]), w1, fmaf(w2, sDirS[jj * 3 + 1], v1));
                    v2 = fmaf(bfu(vp[256]), w1, fmaf(w2, sDirS[jj * 3 + 2], v2));
                }
                if (cut1 != 0.0f) {
                    const unsigned short* vp = srow + (size_t)(jj + 1) * 384 + c;
                    const float w1 = bfhi(p12), w2 = bfhi(p22);
                    v0 = fmaf(bfu(vp[0]),   w1, fmaf(w2, sDirS[jj * 3 + 3], v0));
                    v1 = fmaf(bfu(vp[128]), w1, fmaf(w2, sDirS[jj * 3 + 4], v1));
                    v2 = fmaf(bfu(vp[256]), w1, fmaf(w2, sDirS[jj * 3 + 5], v2));
                }
            }
        }
        __syncthreads();
        p ^= 1;
    }

    // merge the two j-groups
    if (grp == 1) {
        sMrg[c][0] = l;  sMrg[c][1] = A;
        sMrg[c][2] = v0; sMrg[c][3] = v1; sMrg[c][4] = v2;
    }
    __syncthreads();
    if (grp == 0) {
        const float L = l + sMrg[c][0];
        const float Aa = A + sMrg[c][1];
        const float attn = (L > 0.f) ? (Aa * __builtin_amdgcn_rcpf(L)) : 0.f;
        attn_ws[(size_t)row * 128 + c] = attn;
        vec_ws[((size_t)row * 3 + 0) * 128 + c] = v0 + sMrg[c][2];
        vec_ws[((size_t)row * 3 + 1) * 128 + c] = v1 + sMrg[c][3];
        vec_ws[((size_t)row * 3 + 2) * 128 + c] = v2 + sMrg[c][4];
    }
}

// ---------------- Phase C: output projection + epilogue ----------------
__global__ __launch_bounds__(256) void phaseC_kernel(
    const float* __restrict__ Wo, const float* __restrict__ bo,
    const float* __restrict__ attn_ws, const float* __restrict__ veldot_ws,
    const float* __restrict__ w3_ws, const float* __restrict__ vec_ws,
    float* __restrict__ out) {
    const int row = blockIdx.x;
    const int t = threadIdx.x;
    __shared__ float sAttn[128];
    __shared__ float sO[384];
    if (t < 128) sAttn[t] = attn_ws[(size_t)row * 128 + t];
    __syncthreads();
    for (int o = t; o < 384; o += 256) {
        float acc = bo[o];
#pragma unroll 8
        for (int r = 0; r < 128; ++r) acc = fmaf(sAttn[r], Wo[r * 384 + o], acc);
        sO[o] = acc;
    }
    __syncthreads();
    if (t < 128) {
        int c = t;
        float o1 = sO[c], o2 = sO[128 + c], o3 = sO[256 + c];
        float dx = fmaf(veldot_ws[(size_t)row * 128 + c], o2, o3);
        out[(size_t)row * 128 + c] = dx;
#pragma unroll
        for (int s = 0; s < 3; ++s) {
            size_t idx = ((size_t)row * 3 + s) * 128 + c;
            out[131072 + idx] = fmaf(w3_ws[idx], o1, vec_ws[idx]);
        }
    }
}

extern "C" void kernel_launch(void* const* d_in, const int* in_sizes, int n_in,
                              void* d_out, int out_size, void* d_ws, size_t ws_size,
                              hipStream_t stream) {
    (void)in_sizes; (void)n_in; (void)out_size; (void)ws_size;
    const float* query          = (const float*)d_in[0];
    const float* velocity       = (const float*)d_in[1];
    const float* edge_feature   = (const float*)d_in[2];
    const float* edge_direction = (const float*)d_in[3];
    const float* cutoff         = (const float*)d_in[4];
    const float* Wq   = (const float*)d_in[5];  const float* bq   = (const float*)d_in[6];
    const float* Wk   = (const float*)d_in[7];  const float* bk   = (const float*)d_in[8];
    const float* Wv   = (const float*)d_in[9];  const float* bv   = (const float*)d_in[10];
    const float* Wo   = (const float*)d_in[11]; const float* bo   = (const float*)d_in[12];
    const float* Wvel = (const float*)d_in[13]; const float* bvel = (const float*)d_in[14];
    const float* Wdk  = (const float*)d_in[15]; const float* bdk  = (const float*)d_in[16];
    const float* Wdv  = (const float*)d_in[17]; const float* bdv  = (const float*)d_in[18];

    float* ws        = (float*)d_ws;
    float* qs_ws     = ws;              // 131072
    float* kk_ws     = ws + 131072;     // 131072
    float* vproj_ws  = ws + 262144;     // 393216
    float* veldot_ws = ws + 655360;     // 131072
    float* w3_ws     = ws + 786432;     // 393216
    float* attn_ws   = ws + 1179648;    // 131072
    float* vec_ws    = ws + 1310720;    // 393216
    unsigned short* wfrag  = (unsigned short*)(ws + 1703936);  // 32768 shorts
    unsigned short* velb16 = (unsigned short*)(ws + 1720320);  // 1024*384 shorts

    float* out = (float*)d_out;

    hipLaunchKernelGGL(packW_kernel, dim3(16), dim3(256), 0, stream,
        Wdk, Wdv, wfrag);
    hipLaunchKernelGGL(phaseA_kernel, dim3(1024), dim3(256), 0, stream,
        query, velocity, Wq, bq, Wk, bk, Wv, bv, Wvel, bvel,
        qs_ws, kk_ws, vproj_ws, velb16, veldot_ws, w3_ws);
    hipLaunchKernelGGL(phaseB_kernel, dim3(1024), dim3(256), 0, stream,
        edge_feature, edge_direction, cutoff, velb16,
        wfrag, bdk, bdv, qs_ws, kk_ws, vproj_ws, attn_ws, vec_ws);
    hipLaunchKernelGGL(phaseC_kernel, dim3(1024), dim3(256), 0, stream,
        Wo, bo, attn_ws, veldot_ws, w3_ws, vec_ws, out);
}

// Round 17
// 156.935 us; speedup vs baseline: 1.1532x; 1.1532x over previous
//
#include <hip/hip_runtime.h>
#include <hip/hip_bf16.h>
#include <math.h>

#define TT 256          // T
#define EE 128          // E
#define TJ 16           // j-tile
#define SRCB 28672      // bytes per staged tile block: gatesT 16384 | vel 12288
#define TSH 14336       // shorts per tile block

typedef __attribute__((ext_vector_type(8))) short short8v;
typedef __attribute__((ext_vector_type(4))) short short4v;
typedef __attribute__((ext_vector_type(4))) float f32x4;

__device__ __forceinline__ float silu_f(float x) {
    return x * __builtin_amdgcn_rcpf(1.0f + __expf(-x));
}

__device__ __forceinline__ unsigned short f2bf(float f) {
    union { float f; unsigned u; } x; x.f = f;
    unsigned r = (x.u + 0x7FFFu + ((x.u >> 16) & 1u)) >> 16;
    return (unsigned short)r;
}

__device__ __forceinline__ unsigned cvt_pk_bf16(float lo, float hi) {
    unsigned r;
    asm("v_cvt_pk_bf16_f32 %0, %1, %2" : "=v"(r) : "v"(lo), "v"(hi));
    return r;
}

__device__ __forceinline__ float bflo(unsigned u) { return __uint_as_float(u << 16); }
__device__ __forceinline__ float bfhi(unsigned u) { return __uint_as_float(u & 0xffff0000u); }
__device__ __forceinline__ float bfu(unsigned short u) { return __uint_as_float(((unsigned)u) << 16); }

// ---------------- packW: pre-pack MFMA B-fragments (bf16, fragment order) ----------------
__global__ __launch_bounds__(256) void packW_kernel(
    const float* __restrict__ Wdk, const float* __restrict__ Wdv,
    unsigned short* __restrict__ wfrag) {
    const int idx = blockIdx.x * 256 + threadIdx.x;   // 0..4095
    const int lane = idx & 63;
    const int kh = (idx >> 6) & 1;
    const int nn = (idx >> 7) & 7;
    const int w = idx >> 10;                          // 0..3
    const float* Wsel; int wstride, colbase;
    if (w == 0) { Wsel = Wdk; wstride = 128; colbase = 0; }
    else { Wsel = Wdv; wstride = 384; colbase = (w - 1) * 128; }
    const int lrow = lane >> 4;
    const int lcol = lane & 15;
    const int col = colbase + nn * 16 + lcol;
    unsigned short* dst = wfrag + (size_t)idx * 8;
#pragma unroll
    for (int e = 0; e < 8; ++e) {
        const int k = kh * 32 + lrow * 8 + e;
        dst[e] = f2bf(Wsel[k * wstride + col]);
    }
}

// ---------------- Phase A: projections + transposed bf16 gate/vel packing ----------------
// kkvvT per (b, j-tile): gatesT [512 cols][16 rows] bf16, then vel [16][384] bf16.
__global__ __launch_bounds__(256) void phaseA_kernel(
    const float* __restrict__ query, const float* __restrict__ velocity,
    const float* __restrict__ Wq, const float* __restrict__ bq,
    const float* __restrict__ Wk, const float* __restrict__ bk,
    const float* __restrict__ Wv, const float* __restrict__ bv,
    const float* __restrict__ Wvel, const float* __restrict__ bvel,
    float* __restrict__ qs_ws, unsigned short* __restrict__ kkvvT,
    float* __restrict__ veldot_ws, float* __restrict__ w3_ws) {
    const int row = blockIdx.x;           // b*T + i
    const int t = threadIdx.x;
    __shared__ float sIn[EE];
    __shared__ float sVel[3 * EE];
    __shared__ float sVelp[3 * 384];
    if (t < EE) sIn[t] = query[(size_t)row * EE + t];
    for (int idx = t; idx < 3 * EE; idx += 256)
        sVel[idx] = velocity[(size_t)row * 3 * EE + idx];
    __syncthreads();

    unsigned short* tb = kkvvT + (size_t)(row >> 4) * TSH;
    const int r16 = row & 15;
    for (int o = t; o < 640; o += 256) {
        if (o < 128) {
            int c = o;
            float acc = bq[c];
#pragma unroll 8
            for (int r = 0; r < 128; ++r) acc = fmaf(sIn[r], Wq[r * 128 + c], acc);
            qs_ws[(size_t)row * 128 + c] = acc * 0.25f;   // * d^-0.5
        } else if (o < 256) {
            int c = o - 128;
            float acc = bk[c];
#pragma unroll 8
            for (int r = 0; r < 128; ++r) acc = fmaf(sIn[r], Wk[r * 128 + c], acc);
            tb[c * 16 + r16] = f2bf(acc);
        } else {
            int c = o - 256;
            float acc = bv[c];
#pragma unroll 8
            for (int r = 0; r < 128; ++r) acc = fmaf(sIn[r], Wv[r * 384 + c], acc);
            tb[(128 + c) * 16 + r16] = f2bf(acc);
        }
    }
    // bf16 velocity (row-major within tile block)
    for (int idx = t; idx < 384; idx += 256)
        tb[8192 + r16 * 384 + idx] = f2bf(sVel[idx]);

    for (int c = t; c < 384; c += 256) {
        float a0 = bvel[c], a1 = a0, a2 = a0;
#pragma unroll 8
        for (int r = 0; r < 128; ++r) {
            float w = Wvel[r * 384 + c];
            a0 = fmaf(sVel[r], w, a0);
            a1 = fmaf(sVel[128 + r], w, a1);
            a2 = fmaf(sVel[256 + r], w, a2);
        }
        sVelp[0 * 384 + c] = a0;
        sVelp[1 * 384 + c] = a1;
        sVelp[2 * 384 + c] = a2;
    }
    __syncthreads();
    if (t < 128) {
        int c = t;
        float vd = 0.f;
#pragma unroll
        for (int s = 0; s < 3; ++s)
            vd += sVelp[s * 384 + c] * sVelp[s * 384 + 128 + c];
        veldot_ws[(size_t)row * 128 + c] = vd;
#pragma unroll
        for (int s = 0; s < 3; ++s)
            w3_ws[((size_t)row * 3 + s) * 128 + c] = sVelp[s * 384 + 256 + c];
    }
}

// ---------------- Phase B: MFMA edge MLP + elementwise attention ----------------
// Tile blocks (gatesT|vel) async-staged double-buffered; weights in registers.
__global__ __launch_bounds__(256, 2) void phaseB_kernel(
    const float* __restrict__ edge_feature, const float* __restrict__ edge_direction,
    const float* __restrict__ cutoff,
    const unsigned short* __restrict__ wfrag, const unsigned short* __restrict__ kkvvT,
    const float* __restrict__ bdk, const float* __restrict__ bdv,
    const float* __restrict__ qs_ws,
    float* __restrict__ attn_ws, float* __restrict__ vec_ws) {
    // XCD swizzle: xcd = blk%8; each XCD serves one batch-half's L2 reuse set.
    const int blk = blockIdx.x;
    const int x = blk & 7;
    const int slot = blk >> 3;            // 0..127
    const int b = x >> 1;
    const int i = ((x & 1) << 7) + slot;
    const int row = b * TT + i;

    const int t = threadIdx.x;
    const int wave = t >> 6;
    const int lane = t & 63;
    const int lrow = lane >> 4;            // 0..3
    const int lcol = lane & 15;            // 0..15

    __shared__ __align__(16) unsigned char sSrc[2 * SRCB];   // staged tile blocks, dbuf
    __shared__ __align__(16) unsigned char sEFb[16 * 128];   // bf16 EF tile, XOR-swizzled
    __shared__ unsigned short sKD[128 * 18];                 // kk*silu(dk), [c][j]
    __shared__ unsigned short sGV[3 * 128 * 18];             // vproj*silu(dv), [plane][c][j]
    __shared__ float sCut[TJ];
    __shared__ float sDirS[TJ * 3];
    __shared__ float sMrg[128][5];

    const float* Bsel;
    int colbase;
    if (wave == 0) { Bsel = bdk; colbase = 0; }
    else { Bsel = bdv; colbase = (wave - 1) * 128; }

    float biasv[8];
#pragma unroll
    for (int n = 0; n < 8; ++n)
        biasv[n] = Bsel[colbase + n * 16 + lcol];

    // Weight fragments in registers (loaded once; launch_bounds(256,2) -> no spill)
    const unsigned short* wfbase = wfrag + ((size_t)wave * 1024 + lane) * 8;
    short8v bwr[16];
#pragma unroll
    for (int n = 0; n < 8; ++n) {
        bwr[2 * n]     = *(const short8v*)(wfbase + (size_t)n * 1024);
        bwr[2 * n + 1] = *(const short8v*)(wfbase + (size_t)n * 1024 + 512);
    }

    const int grp = t >> 7;        // j-half for attention phase
    const int c = t & 127;         // channel
    const float qsc = qs_ws[(size_t)row * 128 + c] * 0.25f;   // extra /sqrt(d)

    float l = 0.f, A = 0.f;
    float v0 = 0.f, v1 = 0.f, v2 = 0.f;

    const size_t ef_base = (size_t)row * TT * 64;
    const size_t cut_base = (size_t)row * TT;
    const size_t dir_base = (size_t)row * TT * 3;
    const unsigned char* kvT = (const unsigned char*)kkvvT + (size_t)(b * 16) * SRCB;

    const int ldsoff = (t & 192) * 16;    // wave*1024, wave-uniform

    // ---- prologue: async-stage tile 0 into buf 0 ----
#pragma unroll
    for (int r = 0; r < 7; ++r)
        __builtin_amdgcn_global_load_lds(
            (const void*)(kvT + (size_t)r * 4096 + (size_t)t * 16),
            (void*)(sSrc + r * 4096 + ldsoff), 16, 0, 0);

    f32x4 pEf = ((const f32x4*)(edge_feature + ef_base))[t];
    float pCut = (t < TJ) ? cutoff[cut_base + t] : 0.f;
    float pDir = (t < TJ * 3) ? edge_direction[dir_base + t] : 0.f;

    int p = 0;
    for (int j0 = 0; j0 < TT; j0 += TJ) {
        {   // write staged EF tile (bf16, XOR swizzle)
            const int erow = t >> 4;
            const int kq = t & 15;
            unsigned plo = cvt_pk_bf16(pEf[0], pEf[1]);
            unsigned phi = cvt_pk_bf16(pEf[2], pEf[3]);
            const int byteoff = (kq * 8) ^ ((erow & 7) << 4);
            *(int2*)(sEFb + erow * 128 + byteoff) = make_int2((int)plo, (int)phi);
            if (t < TJ) sCut[t] = pCut;
            if (t < TJ * 3) sDirS[t] = pDir;
        }
        __syncthreads();   // drains tile stage -> buf[p] ready; EF tile ready

        // ---- issue async stage for next tile into buf[p^1] ----
        if (j0 + TJ < TT) {
            const unsigned char* src = kvT + (size_t)((j0 >> 4) + 1) * SRCB;
            unsigned char* dst = sSrc + (p ^ 1) * SRCB;
#pragma unroll
            for (int r = 0; r < 7; ++r)
                __builtin_amdgcn_global_load_lds(
                    (const void*)(src + (size_t)r * 4096 + (size_t)t * 16),
                    (void*)(dst + r * 4096 + ldsoff), 16, 0, 0);
        }
        // reg-prefetch next EF/cut/dir (wrap; consumed after next barrier)
        {
            const int jn = (j0 + TJ) & 255;
            pEf = ((const f32x4*)(edge_feature + ef_base + (size_t)jn * 64))[t];
            pCut = (t < TJ) ? cutoff[cut_base + jn + t] : 0.f;
            pDir = (t < TJ * 3) ? edge_direction[dir_base + (size_t)jn * 3 + t] : 0.f;
        }

        // ---- MFMA: [16 j x 64 R] @ [64 x 512] -> silu -> gate product -> LDS ----
        {
            const unsigned short* gT = (const unsigned short*)(sSrc + p * SRCB);
            const int arow = lcol;
            const int swzb = (arow & 7) << 4;
            const short8v a0 = *(const short8v*)(sEFb + arow * 128 + ((lrow * 16) ^ swzb));
            const short8v a1 = *(const short8v*)(sEFb + arow * 128 + ((64 + lrow * 16) ^ swzb));

            // transposed gates: one ds_read_b64 per n = 4 consecutive rows of col
            short4v g4[8];
#pragma unroll
            for (int n = 0; n < 8; ++n)
                g4[n] = *(const short4v*)(gT + ((wave * 128 + n * 16 + lcol) * 16 + lrow * 4));
#pragma unroll
            for (int n = 0; n < 8; ++n) {
                const int col = colbase + n * 16 + lcol;
                f32x4 acc = {biasv[n], biasv[n], biasv[n], biasv[n]};
                acc = __builtin_amdgcn_mfma_f32_16x16x32_bf16(a0, bwr[2 * n],     acc, 0, 0, 0);
                acc = __builtin_amdgcn_mfma_f32_16x16x32_bf16(a1, bwr[2 * n + 1], acc, 0, 0, 0);
                const float r0 = bfu((unsigned short)g4[n][0]) * silu_f(acc[0]);
                const float r1 = bfu((unsigned short)g4[n][1]) * silu_f(acc[1]);
                const float r2 = bfu((unsigned short)g4[n][2]) * silu_f(acc[2]);
                const float r3 = bfu((unsigned short)g4[n][3]) * silu_f(acc[3]);
                const unsigned w01 = cvt_pk_bf16(r0, r1);
                const unsigned w23 = cvt_pk_bf16(r2, r3);
                unsigned short* dst;
                if (wave == 0) {
                    dst = &sKD[col * 18 + lrow * 4];
                } else {
                    const int plane = (col >> 4) % 3;
                    const int cch = (col / 48) * 16 + lcol;
                    dst = &sGV[plane * 2304 + cch * 18 + lrow * 4];
                }
                *(unsigned*)(dst) = w01;
                *(unsigned*)(dst + 2) = w23;
            }
        }
        __syncthreads();   // drains next-tile stage; sKD/sGV visible

        // ---- attention accumulation: 2 j-groups x 128 channels ----
        {
            const unsigned short* svel = (const unsigned short*)(sSrc + p * SRCB + 16384);
            const int jlo = grp * (TJ / 2);
#pragma unroll
            for (int q = 0; q < 4; ++q) {
                const int jj = jlo + 2 * q;
                const unsigned kd2 = *(const unsigned*)(&sKD[c * 18 + jj]);
                const unsigned vg2 = *(const unsigned*)(&sGV[0 * 2304 + c * 18 + jj]);
                const unsigned p12 = *(const unsigned*)(&sGV[1 * 2304 + c * 18 + jj]);
                const unsigned p22 = *(const unsigned*)(&sGV[2 * 2304 + c * 18 + jj]);
                const float cut0 = sCut[jj];
                const float cut1 = sCut[jj + 1];
                const float p0 = __expf(qsc * bflo(kd2));
                const float p1 = __expf(qsc * bfhi(kd2));
                l += p0 + p1;
                A = fmaf(p0 * cut0, bflo(vg2), A);
                A = fmaf(p1 * cut1, bfhi(vg2), A);
                if (cut0 != 0.0f) {
                    const unsigned short* vp = svel + (size_t)jj * 384 + c;
                    const float w1 = bflo(p12), w2 = bflo(p22);
                    v0 = fmaf(bfu(vp[0]),   w1, fmaf(w2, sDirS[jj * 3 + 0], v0));
                    v1 = fmaf(bfu(vp[128]), w1, fmaf(w2, sDirS[jj * 3 + 1], v1));
                    v2 = fmaf(bfu(vp[256]), w1, fmaf(w2, sDirS[jj * 3 + 2], v2));
                }
                if (cut1 != 0.0f) {
                    const unsigned short* vp = svel + (size_t)(jj + 1) * 384 + c;
                    const float w1 = bfhi(p12), w2 = bfhi(p22);
                    v0 = fmaf(bfu(vp[0]),   w1, fmaf(w2, sDirS[jj * 3 + 3], v0));
                    v1 = fmaf(bfu(vp[128]), w1, fmaf(w2, sDirS[jj * 3 + 4], v1));
                    v2 = fmaf(bfu(vp[256]), w1, fmaf(w2, sDirS[jj * 3 + 5], v2));
                }
            }
        }
        __syncthreads();
        p ^= 1;
    }

    // merge the two j-groups
    if (grp == 1) {
        sMrg[c][0] = l;  sMrg[c][1] = A;
        sMrg[c][2] = v0; sMrg[c][3] = v1; sMrg[c][4] = v2;
    }
    __syncthreads();
    if (grp == 0) {
        const float L = l + sMrg[c][0];
        const float Aa = A + sMrg[c][1];
        const float attn = (L > 0.f) ? (Aa * __builtin_amdgcn_rcpf(L)) : 0.f;
        attn_ws[(size_t)row * 128 + c] = attn;
        vec_ws[((size_t)row * 3 + 0) * 128 + c] = v0 + sMrg[c][2];
        vec_ws[((size_t)row * 3 + 1) * 128 + c] = v1 + sMrg[c][3];
        vec_ws[((size_t)row * 3 + 2) * 128 + c] = v2 + sMrg[c][4];
    }
}

// ---------------- Phase C: output projection + epilogue ----------------
__global__ __launch_bounds__(256) void phaseC_kernel(
    const float* __restrict__ Wo, const float* __restrict__ bo,
    const float* __restrict__ attn_ws, const float* __restrict__ veldot_ws,
    const float* __restrict__ w3_ws, const float* __restrict__ vec_ws,
    float* __restrict__ out) {
    const int row = blockIdx.x;
    const int t = threadIdx.x;
    __shared__ float sAttn[128];
    __shared__ float sO[384];
    if (t < 128) sAttn[t] = attn_ws[(size_t)row * 128 + t];
    __syncthreads();
    for (int o = t; o < 384; o += 256) {
        float acc = bo[o];
#pragma unroll 8
        for (int r = 0; r < 128; ++r) acc = fmaf(sAttn[r], Wo[r * 384 + o], acc);
        sO[o] = acc;
    }
    __syncthreads();
    if (t < 128) {
        int c = t;
        float o1 = sO[c], o2 = sO[128 + c], o3 = sO[256 + c];
        float dx = fmaf(veldot_ws[(size_t)row * 128 + c], o2, o3);
        out[(size_t)row * 128 + c] = dx;
#pragma unroll
        for (int s = 0; s < 3; ++s) {
            size_t idx = ((size_t)row * 3 + s) * 128 + c;
            out[131072 + idx] = fmaf(w3_ws[idx], o1, vec_ws[idx]);
        }
    }
}

extern "C" void kernel_launch(void* const* d_in, const int* in_sizes, int n_in,
                              void* d_out, int out_size, void* d_ws, size_t ws_size,
                              hipStream_t stream) {
    (void)in_sizes; (void)n_in; (void)out_size; (void)ws_size;
    const float* query          = (const float*)d_in[0];
    const float* velocity       = (const float*)d_in[1];
    const float* edge_feature   = (const float*)d_in[2];
    const float* edge_direction = (const float*)d_in[3];
    const float* cutoff         = (const float*)d_in[4];
    const float* Wq   = (const float*)d_in[5];  const float* bq   = (const float*)d_in[6];
    const float* Wk   = (const float*)d_in[7];  const float* bk   = (const float*)d_in[8];
    const float* Wv   = (const float*)d_in[9];  const float* bv   = (const float*)d_in[10];
    const float* Wo   = (const float*)d_in[11]; const float* bo   = (const float*)d_in[12];
    const float* Wvel = (const float*)d_in[13]; const float* bvel = (const float*)d_in[14];
    const float* Wdk  = (const float*)d_in[15]; const float* bdk  = (const float*)d_in[16];
    const float* Wdv  = (const float*)d_in[17]; const float* bdv  = (const float*)d_in[18];

    float* ws        = (float*)d_ws;
    float* qs_ws     = ws;              // 131072
    float* veldot_ws = ws + 131072;     // 131072
    float* w3_ws     = ws + 262144;     // 393216
    float* attn_ws   = ws + 655360;     // 131072
    float* vec_ws    = ws + 786432;     // 393216
    unsigned short* wfrag = (unsigned short*)(ws + 1179648);  // 32768 shorts
    unsigned short* kkvvT = (unsigned short*)(ws + 1196032);  // 64 tiles * 14336 shorts

    float* out = (float*)d_out;

    hipLaunchKernelGGL(packW_kernel, dim3(16), dim3(256), 0, stream,
        Wdk, Wdv, wfrag);
    hipLaunchKernelGGL(phaseA_kernel, dim3(1024), dim3(256), 0, stream,
        query, velocity, Wq, bq, Wk, bk, Wv, bv, Wvel, bvel,
        qs_ws, kkvvT, veldot_ws, w3_ws);
    hipLaunchKernelGGL(phaseB_kernel, dim3(1024), dim3(256), 0, stream,
        edge_feature, edge_direction, cutoff,
        wfrag, kkvvT, bdk, bdv, qs_ws, attn_ws, vec_ws);
    hipLaunchKernelGGL(phaseC_kernel, dim3(1024), dim3(256), 0, stream,
        Wo, bo, attn_ws, veldot_ws, w3_ws, vec_ws, out);
}

// Round 18
// 154.020 us; speedup vs baseline: 1.1750x; 1.0189x over previous
//
#include <hip/hip_runtime.h>
#include <hip/hip_bf16.h>
#include <math.h>

#define TT 256          // T
#define EE 128          // E
#define TJ 16           // j-tile
#define SRCB 28672      // bytes per staged tile block: gatesT 16384 | vel 12288
#define TSH 14336       // shorts per tile block

typedef __attribute__((ext_vector_type(8))) short short8v;
typedef __attribute__((ext_vector_type(4))) short short4v;
typedef __attribute__((ext_vector_type(4))) float f32x4;

__device__ __forceinline__ float silu_f(float x) {
    return x * __builtin_amdgcn_rcpf(1.0f + __expf(-x));
}

__device__ __forceinline__ unsigned short f2bf(float f) {
    union { float f; unsigned u; } x; x.f = f;
    unsigned r = (x.u + 0x7FFFu + ((x.u >> 16) & 1u)) >> 16;
    return (unsigned short)r;
}

__device__ __forceinline__ unsigned cvt_pk_bf16(float lo, float hi) {
    unsigned r;
    asm("v_cvt_pk_bf16_f32 %0, %1, %2" : "=v"(r) : "v"(lo), "v"(hi));
    return r;
}

__device__ __forceinline__ float bflo(unsigned u) { return __uint_as_float(u << 16); }
__device__ __forceinline__ float bfhi(unsigned u) { return __uint_as_float(u & 0xffff0000u); }
__device__ __forceinline__ float bfu(unsigned short u) { return __uint_as_float(((unsigned)u) << 16); }

// ---------------- packW: pre-pack MFMA B-fragments (bf16, fragment order) ----------------
__global__ __launch_bounds__(256) void packW_kernel(
    const float* __restrict__ Wdk, const float* __restrict__ Wdv,
    unsigned short* __restrict__ wfrag) {
    const int idx = blockIdx.x * 256 + threadIdx.x;   // 0..4095
    const int lane = idx & 63;
    const int kh = (idx >> 6) & 1;
    const int nn = (idx >> 7) & 7;
    const int w = idx >> 10;                          // 0..3
    const float* Wsel; int wstride, colbase;
    if (w == 0) { Wsel = Wdk; wstride = 128; colbase = 0; }
    else { Wsel = Wdv; wstride = 384; colbase = (w - 1) * 128; }
    const int lrow = lane >> 4;
    const int lcol = lane & 15;
    const int col = colbase + nn * 16 + lcol;
    unsigned short* dst = wfrag + (size_t)idx * 8;
#pragma unroll
    for (int e = 0; e < 8; ++e) {
        const int k = kh * 32 + lrow * 8 + e;
        dst[e] = f2bf(Wsel[k * wstride + col]);
    }
}

// ---------------- Phase A: projections + transposed bf16 gate/vel packing ----------------
// kkvvT per (b, j-tile): gatesT [512 cols][16 rows] bf16, then vel [16][384] bf16.
__global__ __launch_bounds__(256) void phaseA_kernel(
    const float* __restrict__ query, const float* __restrict__ velocity,
    const float* __restrict__ Wq, const float* __restrict__ bq,
    const float* __restrict__ Wk, const float* __restrict__ bk,
    const float* __restrict__ Wv, const float* __restrict__ bv,
    const float* __restrict__ Wvel, const float* __restrict__ bvel,
    float* __restrict__ qs_ws, unsigned short* __restrict__ kkvvT,
    float* __restrict__ veldot_ws, float* __restrict__ w3_ws) {
    const int row = blockIdx.x;           // b*T + i
    const int t = threadIdx.x;
    __shared__ float sIn[EE];
    __shared__ float sVel[3 * EE];
    __shared__ float sVelp[3 * 384];
    if (t < EE) sIn[t] = query[(size_t)row * EE + t];
    for (int idx = t; idx < 3 * EE; idx += 256)
        sVel[idx] = velocity[(size_t)row * 3 * EE + idx];
    __syncthreads();

    unsigned short* tb = kkvvT + (size_t)(row >> 4) * TSH;
    const int r16 = row & 15;
    for (int o = t; o < 640; o += 256) {
        if (o < 128) {
            int c = o;
            float acc = bq[c];
#pragma unroll 8
            for (int r = 0; r < 128; ++r) acc = fmaf(sIn[r], Wq[r * 128 + c], acc);
            qs_ws[(size_t)row * 128 + c] = acc * 0.25f;   // * d^-0.5
        } else if (o < 256) {
            int c = o - 128;
            float acc = bk[c];
#pragma unroll 8
            for (int r = 0; r < 128; ++r) acc = fmaf(sIn[r], Wk[r * 128 + c], acc);
            tb[c * 16 + r16] = f2bf(acc);
        } else {
            int c = o - 256;
            float acc = bv[c];
#pragma unroll 8
            for (int r = 0; r < 128; ++r) acc = fmaf(sIn[r], Wv[r * 384 + c], acc);
            tb[(128 + c) * 16 + r16] = f2bf(acc);
        }
    }
    // bf16 velocity (row-major within tile block)
    for (int idx = t; idx < 384; idx += 256)
        tb[8192 + r16 * 384 + idx] = f2bf(sVel[idx]);

    for (int c = t; c < 384; c += 256) {
        float a0 = bvel[c], a1 = a0, a2 = a0;
#pragma unroll 8
        for (int r = 0; r < 128; ++r) {
            float w = Wvel[r * 384 + c];
            a0 = fmaf(sVel[r], w, a0);
            a1 = fmaf(sVel[128 + r], w, a1);
            a2 = fmaf(sVel[256 + r], w, a2);
        }
        sVelp[0 * 384 + c] = a0;
        sVelp[1 * 384 + c] = a1;
        sVelp[2 * 384 + c] = a2;
    }
    __syncthreads();
    if (t < 128) {
        int c = t;
        float vd = 0.f;
#pragma unroll
        for (int s = 0; s < 3; ++s)
            vd += sVelp[s * 384 + c] * sVelp[s * 384 + 128 + c];
        veldot_ws[(size_t)row * 128 + c] = vd;
#pragma unroll
        for (int s = 0; s < 3; ++s)
            w3_ws[((size_t)row * 3 + s) * 128 + c] = sVelp[s * 384 + 256 + c];
    }
}

// ---------------- Phase B: MFMA edge MLP + elementwise attention ----------------
// Single staged buffer, phase-split async staging:
//   after barrier B (gates dead): stage gates(t+1), hides under attention;
//   after barrier C (vel dead):   stage vel(t+1), drains at next barrier A.
__global__ __launch_bounds__(256, 3) void phaseB_kernel(
    const float* __restrict__ edge_feature, const float* __restrict__ edge_direction,
    const float* __restrict__ cutoff,
    const unsigned short* __restrict__ wfrag, const unsigned short* __restrict__ kkvvT,
    const float* __restrict__ bdk, const float* __restrict__ bdv,
    const float* __restrict__ qs_ws,
    float* __restrict__ attn_ws, float* __restrict__ vec_ws) {
    // XCD swizzle: xcd = blk%8; each XCD serves one batch-half's L2 reuse set.
    const int blk = blockIdx.x;
    const int x = blk & 7;
    const int slot = blk >> 3;            // 0..127
    const int b = x >> 1;
    const int i = ((x & 1) << 7) + slot;
    const int row = b * TT + i;

    const int t = threadIdx.x;
    const int wave = t >> 6;
    const int lane = t & 63;
    const int lrow = lane >> 4;            // 0..3
    const int lcol = lane & 15;            // 0..15

    __shared__ __align__(16) unsigned char sSrc[SRCB];       // staged tile block (single)
    __shared__ __align__(16) unsigned char sEFb[16 * 128];   // bf16 EF tile, XOR-swizzled
    __shared__ unsigned short sKD[128 * 18];                 // kk*silu(dk), [c][j]
    __shared__ unsigned short sGV[3 * 128 * 18];             // vproj*silu(dv), [plane][c][j]
    __shared__ float sCut[TJ];
    __shared__ float sDirS[TJ * 3];
    __shared__ float sMrg[128][5];

    const float* Bsel;
    int colbase;
    if (wave == 0) { Bsel = bdk; colbase = 0; }
    else { Bsel = bdv; colbase = (wave - 1) * 128; }

    float biasv[8];
#pragma unroll
    for (int n = 0; n < 8; ++n)
        biasv[n] = Bsel[colbase + n * 16 + lcol];

    // Weight fragments in registers (loaded once)
    const unsigned short* wfbase = wfrag + ((size_t)wave * 1024 + lane) * 8;
    short8v bwr[16];
#pragma unroll
    for (int n = 0; n < 8; ++n) {
        bwr[2 * n]     = *(const short8v*)(wfbase + (size_t)n * 1024);
        bwr[2 * n + 1] = *(const short8v*)(wfbase + (size_t)n * 1024 + 512);
    }

    const int grp = t >> 7;        // j-half for attention phase
    const int c = t & 127;         // channel
    const float qsc = qs_ws[(size_t)row * 128 + c] * 0.25f;   // extra /sqrt(d)

    float l = 0.f, A = 0.f;
    float v0 = 0.f, v1 = 0.f, v2 = 0.f;

    const size_t ef_base = (size_t)row * TT * 64;
    const size_t cut_base = (size_t)row * TT;
    const size_t dir_base = (size_t)row * TT * 3;
    const unsigned char* kvT = (const unsigned char*)kkvvT + (size_t)(b * 16) * SRCB;

    const int ldsoff = (t & 192) * 16;    // wave*1024, wave-uniform

    // ---- prologue: async-stage full tile 0 ----
#pragma unroll
    for (int r = 0; r < 7; ++r)
        __builtin_amdgcn_global_load_lds(
            (const void*)(kvT + (size_t)r * 4096 + (size_t)t * 16),
            (void*)(sSrc + r * 4096 + ldsoff), 16, 0, 0);

    f32x4 pEf = ((const f32x4*)(edge_feature + ef_base))[t];
    float pCut = (t < TJ) ? cutoff[cut_base + t] : 0.f;
    float pDir = (t < TJ * 3) ? edge_direction[dir_base + t] : 0.f;

    for (int j0 = 0; j0 < TT; j0 += TJ) {
        {   // write staged EF tile (bf16, XOR swizzle)
            const int erow = t >> 4;
            const int kq = t & 15;
            unsigned plo = cvt_pk_bf16(pEf[0], pEf[1]);
            unsigned phi = cvt_pk_bf16(pEf[2], pEf[3]);
            const int byteoff = (kq * 8) ^ ((erow & 7) << 4);
            *(int2*)(sEFb + erow * 128 + byteoff) = make_int2((int)plo, (int)phi);
            if (t < TJ) sCut[t] = pCut;
            if (t < TJ * 3) sDirS[t] = pDir;
        }
        __syncthreads();   // A: drains pending stage (vel or full tile); EF ready

        // reg-prefetch next EF/cut/dir (wrap; consumed after next barrier A)
        {
            const int jn = (j0 + TJ) & 255;
            pEf = ((const f32x4*)(edge_feature + ef_base + (size_t)jn * 64))[t];
            pCut = (t < TJ) ? cutoff[cut_base + jn + t] : 0.f;
            pDir = (t < TJ * 3) ? edge_direction[dir_base + (size_t)jn * 3 + t] : 0.f;
        }

        // ---- MFMA: [16 j x 64 R] @ [64 x 512] -> silu -> gate product -> LDS ----
        {
            const unsigned short* gT = (const unsigned short*)sSrc;
            const int arow = lcol;
            const int swzb = (arow & 7) << 4;
            const short8v a0 = *(const short8v*)(sEFb + arow * 128 + ((lrow * 16) ^ swzb));
            const short8v a1 = *(const short8v*)(sEFb + arow * 128 + ((64 + lrow * 16) ^ swzb));

            // transposed gates: one ds_read_b64 per n = 4 consecutive rows of col
            short4v g4[8];
#pragma unroll
            for (int n = 0; n < 8; ++n)
                g4[n] = *(const short4v*)(gT + ((wave * 128 + n * 16 + lcol) * 16 + lrow * 4));
#pragma unroll
            for (int n = 0; n < 8; ++n) {
                const int col = colbase + n * 16 + lcol;
                f32x4 acc = {biasv[n], biasv[n], biasv[n], biasv[n]};
                acc = __builtin_amdgcn_mfma_f32_16x16x32_bf16(a0, bwr[2 * n],     acc, 0, 0, 0);
                acc = __builtin_amdgcn_mfma_f32_16x16x32_bf16(a1, bwr[2 * n + 1], acc, 0, 0, 0);
                const float r0 = bfu((unsigned short)g4[n][0]) * silu_f(acc[0]);
                const float r1 = bfu((unsigned short)g4[n][1]) * silu_f(acc[1]);
                const float r2 = bfu((unsigned short)g4[n][2]) * silu_f(acc[2]);
                const float r3 = bfu((unsigned short)g4[n][3]) * silu_f(acc[3]);
                const unsigned w01 = cvt_pk_bf16(r0, r1);
                const unsigned w23 = cvt_pk_bf16(r2, r3);
                unsigned short* dst;
                if (wave == 0) {
                    dst = &sKD[col * 18 + lrow * 4];
                } else {
                    const int plane = (col >> 4) % 3;
                    const int cch = (col / 48) * 16 + lcol;
                    dst = &sGV[plane * 2304 + cch * 18 + lrow * 4];
                }
                *(unsigned*)(dst) = w01;
                *(unsigned*)(dst + 2) = w23;
            }
        }
        __syncthreads();   // B: gates(t) dead; sKD/sGV visible

        // ---- issue gate-stage(t+1) (hides under attention; drains at C) ----
        if (j0 + TJ < TT) {
            const unsigned char* src = kvT + (size_t)((j0 >> 4) + 1) * SRCB;
#pragma unroll
            for (int r = 0; r < 4; ++r)
                __builtin_amdgcn_global_load_lds(
                    (const void*)(src + (size_t)r * 4096 + (size_t)t * 16),
                    (void*)(sSrc + r * 4096 + ldsoff), 16, 0, 0);
        }

        // ---- attention accumulation: 2 j-groups x 128 channels ----
        {
            const unsigned short* svel = (const unsigned short*)(sSrc + 16384);
            const int jlo = grp * (TJ / 2);
#pragma unroll
            for (int q = 0; q < 4; ++q) {
                const int jj = jlo + 2 * q;
                const unsigned kd2 = *(const unsigned*)(&sKD[c * 18 + jj]);
                const unsigned vg2 = *(const unsigned*)(&sGV[0 * 2304 + c * 18 + jj]);
                const unsigned p12 = *(const unsigned*)(&sGV[1 * 2304 + c * 18 + jj]);
                const unsigned p22 = *(const unsigned*)(&sGV[2 * 2304 + c * 18 + jj]);
                const float cut0 = sCut[jj];
                const float cut1 = sCut[jj + 1];
                const float p0 = __expf(qsc * bflo(kd2));
                const float p1 = __expf(qsc * bfhi(kd2));
                l += p0 + p1;
                A = fmaf(p0 * cut0, bflo(vg2), A);
                A = fmaf(p1 * cut1, bfhi(vg2), A);
                if (cut0 != 0.0f) {
                    const unsigned short* vp = svel + (size_t)jj * 384 + c;
                    const float w1 = bflo(p12), w2 = bflo(p22);
                    v0 = fmaf(bfu(vp[0]),   w1, fmaf(w2, sDirS[jj * 3 + 0], v0));
                    v1 = fmaf(bfu(vp[128]), w1, fmaf(w2, sDirS[jj * 3 + 1], v1));
                    v2 = fmaf(bfu(vp[256]), w1, fmaf(w2, sDirS[jj * 3 + 2], v2));
                }
                if (cut1 != 0.0f) {
                    const unsigned short* vp = svel + (size_t)(jj + 1) * 384 + c;
                    const float w1 = bfhi(p12), w2 = bfhi(p22);
                    v0 = fmaf(bfu(vp[0]),   w1, fmaf(w2, sDirS[jj * 3 + 3], v0));
                    v1 = fmaf(bfu(vp[128]), w1, fmaf(w2, sDirS[jj * 3 + 4], v1));
                    v2 = fmaf(bfu(vp[256]), w1, fmaf(w2, sDirS[jj * 3 + 5], v2));
                }
            }
        }
        __syncthreads();   // C: vel(t) dead; gate-stage(t+1) drained

        // ---- issue vel-stage(t+1) (overlaps EF-write; drains at next A) ----
        if (j0 + TJ < TT) {
            const unsigned char* src = kvT + (size_t)((j0 >> 4) + 1) * SRCB;
#pragma unroll
            for (int r = 4; r < 7; ++r)
                __builtin_amdgcn_global_load_lds(
                    (const void*)(src + (size_t)r * 4096 + (size_t)t * 16),
                    (void*)(sSrc + r * 4096 + ldsoff), 16, 0, 0);
        }
    }

    // merge the two j-groups
    if (grp == 1) {
        sMrg[c][0] = l;  sMrg[c][1] = A;
        sMrg[c][2] = v0; sMrg[c][3] = v1; sMrg[c][4] = v2;
    }
    __syncthreads();
    if (grp == 0) {
        const float L = l + sMrg[c][0];
        const float Aa = A + sMrg[c][1];
        const float attn = (L > 0.f) ? (Aa * __builtin_amdgcn_rcpf(L)) : 0.f;
        attn_ws[(size_t)row * 128 + c] = attn;
        vec_ws[((size_t)row * 3 + 0) * 128 + c] = v0 + sMrg[c][2];
        vec_ws[((size_t)row * 3 + 1) * 128 + c] = v1 + sMrg[c][3];
        vec_ws[((size_t)row * 3 + 2) * 128 + c] = v2 + sMrg[c][4];
    }
}

// ---------------- Phase C: output projection + epilogue ----------------
__global__ __launch_bounds__(256) void phaseC_kernel(
    const float* __restrict__ Wo, const float* __restrict__ bo,
    const float* __restrict__ attn_ws, const float* __restrict__ veldot_ws,
    const float* __restrict__ w3_ws, const float* __restrict__ vec_ws,
    float* __restrict__ out) {
    const int row = blockIdx.x;
    const int t = threadIdx.x;
    __shared__ float sAttn[128];
    __shared__ float sO[384];
    if (t < 128) sAttn[t] = attn_ws[(size_t)row * 128 + t];
    __syncthreads();
    for (int o = t; o < 384; o += 256) {
        float acc = bo[o];
#pragma unroll 8
        for (int r = 0; r < 128; ++r) acc = fmaf(sAttn[r], Wo[r * 384 + o], acc);
        sO[o] = acc;
    }
    __syncthreads();
    if (t < 128) {
        int c = t;
        float o1 = sO[c], o2 = sO[128 + c], o3 = sO[256 + c];
        float dx = fmaf(veldot_ws[(size_t)row * 128 + c], o2, o3);
        out[(size_t)row * 128 + c] = dx;
#pragma unroll
        for (int s = 0; s < 3; ++s) {
            size_t idx = ((size_t)row * 3 + s) * 128 + c;
            out[131072 + idx] = fmaf(w3_ws[idx], o1, vec_ws[idx]);
        }
    }
}

extern "C" void kernel_launch(void* const* d_in, const int* in_sizes, int n_in,
                              void* d_out, int out_size, void* d_ws, size_t ws_size,
                              hipStream_t stream) {
    (void)in_sizes; (void)n_in; (void)out_size; (void)ws_size;
    const float* query          = (const float*)d_in[0];
    const float* velocity       = (const float*)d_in[1];
    const float* edge_feature   = (const float*)d_in[2];
    const float* edge_direction = (const float*)d_in[3];
    const float* cutoff         = (const float*)d_in[4];
    const float* Wq   = (const float*)d_in[5];  const float* bq   = (const float*)d_in[6];
    const float* Wk   = (const float*)d_in[7];  const float* bk   = (const float*)d_in[8];
    const float* Wv   = (const float*)d_in[9];  const float* bv   = (const float*)d_in[10];
    const float* Wo   = (const float*)d_in[11]; const float* bo   = (const float*)d_in[12];
    const float* Wvel = (const float*)d_in[13]; const float* bvel = (const float*)d_in[14];
    const float* Wdk  = (const float*)d_in[15]; const float* bdk  = (const float*)d_in[16];
    const float* Wdv  = (const float*)d_in[17]; const float* bdv  = (const float*)d_in[18];

    float* ws        = (float*)d_ws;
    float* qs_ws     = ws;              // 131072
    float* veldot_ws = ws + 131072;     // 131072
    float* w3_ws     = ws + 262144;     // 393216
    float* attn_ws   = ws + 655360;     // 131072
    float* vec_ws    = ws + 786432;     // 393216
    unsigned short* wfrag = (unsigned short*)(ws + 1179648);  // 32768 shorts
    unsigned short* kkvvT = (unsigned short*)(ws + 1196032);  // 64 tiles * 14336 shorts

    float* out = (float*)d_out;

    hipLaunchKernelGGL(packW_kernel, dim3(16), dim3(256), 0, stream,
        Wdk, Wdv, wfrag);
    hipLaunchKernelGGL(phaseA_kernel, dim3(1024), dim3(256), 0, stream,
        query, velocity, Wq, bq, Wk, bk, Wv, bv, Wvel, bvel,
        qs_ws, kkvvT, veldot_ws, w3_ws);
    hipLaunchKernelGGL(phaseB_kernel, dim3(1024), dim3(256), 0, stream,
        edge_feature, edge_direction, cutoff,
        wfrag, kkvvT, bdk, bdv, qs_ws, attn_ws, vec_ws);
    hipLaunchKernelGGL(phaseC_kernel, dim3(1024), dim3(256), 0, stream,
        Wo, bo, attn_ws, veldot_ws, w3_ws, vec_ws, out);
}

// Round 19
// 150.409 us; speedup vs baseline: 1.2032x; 1.0240x over previous
//
#include <hip/hip_runtime.h>
#include <hip/hip_bf16.h>
#include <math.h>

#define TT 256          // T
#define EE 128          // E
#define TJ 16           // j-tile
#define SRCB 28672      // bytes per staged tile block: gatesT 16384 | vel 12288
#define TSH 14336       // shorts per tile block

typedef __attribute__((ext_vector_type(8))) short short8v;
typedef __attribute__((ext_vector_type(4))) short short4v;
typedef __attribute__((ext_vector_type(4))) float f32x4;

__device__ __forceinline__ float silu_f(float x) {
    return x * __builtin_amdgcn_rcpf(1.0f + __expf(-x));
}

__device__ __forceinline__ unsigned short f2bf(float f) {
    union { float f; unsigned u; } x; x.f = f;
    unsigned r = (x.u + 0x7FFFu + ((x.u >> 16) & 1u)) >> 16;
    return (unsigned short)r;
}

__device__ __forceinline__ unsigned cvt_pk_bf16(float lo, float hi) {
    unsigned r;
    asm("v_cvt_pk_bf16_f32 %0, %1, %2" : "=v"(r) : "v"(lo), "v"(hi));
    return r;
}

__device__ __forceinline__ float bflo(unsigned u) { return __uint_as_float(u << 16); }
__device__ __forceinline__ float bfhi(unsigned u) { return __uint_as_float(u & 0xffff0000u); }
__device__ __forceinline__ float bfu(unsigned short u) { return __uint_as_float(((unsigned)u) << 16); }

// ---------------- packW: pre-pack MFMA B-fragments (bf16, fragment order) ----------------
__global__ __launch_bounds__(256) void packW_kernel(
    const float* __restrict__ Wdk, const float* __restrict__ Wdv,
    unsigned short* __restrict__ wfrag) {
    const int idx = blockIdx.x * 256 + threadIdx.x;   // 0..4095
    const int lane = idx & 63;
    const int kh = (idx >> 6) & 1;
    const int nn = (idx >> 7) & 7;
    const int w = idx >> 10;                          // 0..3
    const float* Wsel; int wstride, colbase;
    if (w == 0) { Wsel = Wdk; wstride = 128; colbase = 0; }
    else { Wsel = Wdv; wstride = 384; colbase = (w - 1) * 128; }
    const int lrow = lane >> 4;
    const int lcol = lane & 15;
    const int col = colbase + nn * 16 + lcol;
    unsigned short* dst = wfrag + (size_t)idx * 8;
#pragma unroll
    for (int e = 0; e < 8; ++e) {
        const int k = kh * 32 + lrow * 8 + e;
        dst[e] = f2bf(Wsel[k * wstride + col]);
    }
}

// ---------------- Phase A: projections + transposed bf16 gate/vel packing ----------------
// kkvvT per (b, j-tile): gatesT [512 cols][16 rows] bf16 (XOR-swizzled row groups:
// group' = (row>>2) ^ ((col>>2)&3)), then vel [16][384] bf16.
__global__ __launch_bounds__(256) void phaseA_kernel(
    const float* __restrict__ query, const float* __restrict__ velocity,
    const float* __restrict__ Wq, const float* __restrict__ bq,
    const float* __restrict__ Wk, const float* __restrict__ bk,
    const float* __restrict__ Wv, const float* __restrict__ bv,
    const float* __restrict__ Wvel, const float* __restrict__ bvel,
    float* __restrict__ qs_ws, unsigned short* __restrict__ kkvvT,
    float* __restrict__ veldot_ws, float* __restrict__ w3_ws) {
    const int row = blockIdx.x;           // b*T + i
    const int t = threadIdx.x;
    __shared__ float sIn[EE];
    __shared__ float sVel[3 * EE];
    __shared__ float sVelp[3 * 384];
    if (t < EE) sIn[t] = query[(size_t)row * EE + t];
    for (int idx = t; idx < 3 * EE; idx += 256)
        sVel[idx] = velocity[(size_t)row * 3 * EE + idx];
    __syncthreads();

    unsigned short* tb = kkvvT + (size_t)(row >> 4) * TSH;
    const int r16 = row & 15;
    for (int o = t; o < 640; o += 256) {
        if (o < 128) {
            int c = o;
            float acc = bq[c];
#pragma unroll 8
            for (int r = 0; r < 128; ++r) acc = fmaf(sIn[r], Wq[r * 128 + c], acc);
            qs_ws[(size_t)row * 128 + c] = acc * 0.25f;   // * d^-0.5
        } else if (o < 256) {
            int c = o - 128;
            float acc = bk[c];
#pragma unroll 8
            for (int r = 0; r < 128; ++r) acc = fmaf(sIn[r], Wk[r * 128 + c], acc);
            const int sg = (r16 >> 2) ^ ((c >> 2) & 3);
            tb[c * 16 + sg * 4 + (r16 & 3)] = f2bf(acc);
        } else {
            int c = o - 256;
            float acc = bv[c];
#pragma unroll 8
            for (int r = 0; r < 128; ++r) acc = fmaf(sIn[r], Wv[r * 384 + c], acc);
            const int col = 128 + c;
            const int sg = (r16 >> 2) ^ ((col >> 2) & 3);
            tb[col * 16 + sg * 4 + (r16 & 3)] = f2bf(acc);
        }
    }
    // bf16 velocity (row-major within tile block)
    for (int idx = t; idx < 384; idx += 256)
        tb[8192 + r16 * 384 + idx] = f2bf(sVel[idx]);

    for (int c = t; c < 384; c += 256) {
        float a0 = bvel[c], a1 = a0, a2 = a0;
#pragma unroll 8
        for (int r = 0; r < 128; ++r) {
            float w = Wvel[r * 384 + c];
            a0 = fmaf(sVel[r], w, a0);
            a1 = fmaf(sVel[128 + r], w, a1);
            a2 = fmaf(sVel[256 + r], w, a2);
        }
        sVelp[0 * 384 + c] = a0;
        sVelp[1 * 384 + c] = a1;
        sVelp[2 * 384 + c] = a2;
    }
    __syncthreads();
    if (t < 128) {
        int c = t;
        float vd = 0.f;
#pragma unroll
        for (int s = 0; s < 3; ++s)
            vd += sVelp[s * 384 + c] * sVelp[s * 384 + 128 + c];
        veldot_ws[(size_t)row * 128 + c] = vd;
#pragma unroll
        for (int s = 0; s < 3; ++s)
            w3_ws[((size_t)row * 3 + s) * 128 + c] = sVelp[s * 384 + 256 + c];
    }
}

// ---------------- Phase B: MFMA edge MLP + elementwise attention ----------------
// Single staged buffer, phase-split async staging:
//   after barrier B (gates dead): stage gates(t+1), hides under attention;
//   after barrier C (vel dead):   stage vel(t+1), drains at next barrier A.
__global__ __launch_bounds__(256, 3) void phaseB_kernel(
    const float* __restrict__ edge_feature, const float* __restrict__ edge_direction,
    const float* __restrict__ cutoff,
    const unsigned short* __restrict__ wfrag, const unsigned short* __restrict__ kkvvT,
    const float* __restrict__ bdk, const float* __restrict__ bdv,
    const float* __restrict__ qs_ws,
    float* __restrict__ attn_ws, float* __restrict__ vec_ws) {
    // XCD swizzle: xcd = blk%8; each XCD serves one batch-half's L2 reuse set.
    const int blk = blockIdx.x;
    const int x = blk & 7;
    const int slot = blk >> 3;            // 0..127
    const int b = x >> 1;
    const int i = ((x & 1) << 7) + slot;
    const int row = b * TT + i;

    const int t = threadIdx.x;
    const int wave = t >> 6;
    const int lane = t & 63;
    const int lrow = lane >> 4;            // 0..3
    const int lcol = lane & 15;            // 0..15

    __shared__ __align__(16) unsigned char sSrc[SRCB];       // staged tile block (single)
    __shared__ __align__(16) unsigned char sEFb[16 * 128];   // bf16 EF tile, XOR-swizzled
    __shared__ unsigned short sKD[128 * 18];                 // kk*silu(dk), [c][j]
    __shared__ unsigned short sGV[3 * 128 * 18];             // vproj*silu(dv), [plane][c][j]
    __shared__ float sCut[TJ];
    __shared__ float sDirS[TJ * 3];
    __shared__ float sMrg[128][5];

    const float* Bsel;
    int colbase;
    if (wave == 0) { Bsel = bdk; colbase = 0; }
    else { Bsel = bdv; colbase = (wave - 1) * 128; }

    float biasv[8];
#pragma unroll
    for (int n = 0; n < 8; ++n)
        biasv[n] = Bsel[colbase + n * 16 + lcol];

    // Weight fragments in registers (loaded once)
    const unsigned short* wfbase = wfrag + ((size_t)wave * 1024 + lane) * 8;
    short8v bwr[16];
#pragma unroll
    for (int n = 0; n < 8; ++n) {
        bwr[2 * n]     = *(const short8v*)(wfbase + (size_t)n * 1024);
        bwr[2 * n + 1] = *(const short8v*)(wfbase + (size_t)n * 1024 + 512);
    }

    const int grp = t >> 7;        // j-half for attention phase
    const int c = t & 127;         // channel
    const float qsc = qs_ws[(size_t)row * 128 + c] * 0.25f;   // extra /sqrt(d)

    float l = 0.f, A = 0.f;
    float v0 = 0.f, v1 = 0.f, v2 = 0.f;

    const size_t ef_base = (size_t)row * TT * 64;
    const size_t cut_base = (size_t)row * TT;
    const size_t dir_base = (size_t)row * TT * 3;
    const unsigned char* kvT = (const unsigned char*)kkvvT + (size_t)(b * 16) * SRCB;

    const int ldsoff = (t & 192) * 16;    // wave*1024, wave-uniform
    const int gswz = (lrow ^ ((lcol >> 2) & 3)) * 4;   // swizzled row-group offset

    // ---- prologue: async-stage full tile 0 ----
#pragma unroll
    for (int r = 0; r < 7; ++r)
        __builtin_amdgcn_global_load_lds(
            (const void*)(kvT + (size_t)r * 4096 + (size_t)t * 16),
            (void*)(sSrc + r * 4096 + ldsoff), 16, 0, 0);

    f32x4 pEf = ((const f32x4*)(edge_feature + ef_base))[t];
    float pCut = (t < TJ) ? cutoff[cut_base + t] : 0.f;
    float pDir = (t < TJ * 3) ? edge_direction[dir_base + t] : 0.f;

    for (int j0 = 0; j0 < TT; j0 += TJ) {
        {   // write staged EF tile (bf16, XOR swizzle)
            const int erow = t >> 4;
            const int kq = t & 15;
            unsigned plo = cvt_pk_bf16(pEf[0], pEf[1]);
            unsigned phi = cvt_pk_bf16(pEf[2], pEf[3]);
            const int byteoff = (kq * 8) ^ ((erow & 7) << 4);
            *(int2*)(sEFb + erow * 128 + byteoff) = make_int2((int)plo, (int)phi);
            if (t < TJ) sCut[t] = pCut;
            if (t < TJ * 3) sDirS[t] = pDir;
        }
        __syncthreads();   // A: drains pending stage (vel or full tile); EF ready

        // reg-prefetch next EF/cut/dir (wrap; consumed after next barrier A)
        {
            const int jn = (j0 + TJ) & 255;
            pEf = ((const f32x4*)(edge_feature + ef_base + (size_t)jn * 64))[t];
            pCut = (t < TJ) ? cutoff[cut_base + jn + t] : 0.f;
            pDir = (t < TJ * 3) ? edge_direction[dir_base + (size_t)jn * 3 + t] : 0.f;
        }

        // ---- MFMA: [16 j x 64 R] @ [64 x 512] -> silu -> gate product -> LDS ----
        {
            const unsigned short* gT = (const unsigned short*)sSrc;
            const int arow = lcol;
            const int swzb = (arow & 7) << 4;
            const short8v a0 = *(const short8v*)(sEFb + arow * 128 + ((lrow * 16) ^ swzb));
            const short8v a1 = *(const short8v*)(sEFb + arow * 128 + ((64 + lrow * 16) ^ swzb));

            // transposed gates: one ds_read_b64 per n, bank-swizzled row groups
            short4v g4[8];
#pragma unroll
            for (int n = 0; n < 8; ++n)
                g4[n] = *(const short4v*)(gT + ((wave * 128 + n * 16 + lcol) * 16 + gswz));
#pragma unroll
            for (int n = 0; n < 8; ++n) {
                const int col = colbase + n * 16 + lcol;
                f32x4 acc = {biasv[n], biasv[n], biasv[n], biasv[n]};
                acc = __builtin_amdgcn_mfma_f32_16x16x32_bf16(a0, bwr[2 * n],     acc, 0, 0, 0);
                acc = __builtin_amdgcn_mfma_f32_16x16x32_bf16(a1, bwr[2 * n + 1], acc, 0, 0, 0);
                const float r0 = bfu((unsigned short)g4[n][0]) * silu_f(acc[0]);
                const float r1 = bfu((unsigned short)g4[n][1]) * silu_f(acc[1]);
                const float r2 = bfu((unsigned short)g4[n][2]) * silu_f(acc[2]);
                const float r3 = bfu((unsigned short)g4[n][3]) * silu_f(acc[3]);
                const unsigned w01 = cvt_pk_bf16(r0, r1);
                const unsigned w23 = cvt_pk_bf16(r2, r3);
                unsigned short* dst;
                if (wave == 0) {
                    dst = &sKD[col * 18 + lrow * 4];
                } else {
                    const int plane = (col >> 4) % 3;
                    const int cch = (col / 48) * 16 + lcol;
                    dst = &sGV[plane * 2304 + cch * 18 + lrow * 4];
                }
                *(unsigned*)(dst) = w01;
                *(unsigned*)(dst + 2) = w23;
            }
        }
        __syncthreads();   // B: gates(t) dead; sKD/sGV visible

        // ---- issue gate-stage(t+1) (hides under attention; drains at C) ----
        if (j0 + TJ < TT) {
            const unsigned char* src = kvT + (size_t)((j0 >> 4) + 1) * SRCB;
#pragma unroll
            for (int r = 0; r < 4; ++r)
                __builtin_amdgcn_global_load_lds(
                    (const void*)(src + (size_t)r * 4096 + (size_t)t * 16),
                    (void*)(sSrc + r * 4096 + ldsoff), 16, 0, 0);
        }

        // ---- attention accumulation: 2 j-groups x 128 channels ----
        {
            const unsigned short* svel = (const unsigned short*)(sSrc + 16384);
            const int jlo = grp * (TJ / 2);
#pragma unroll
            for (int q = 0; q < 4; ++q) {
                const int jj = jlo + 2 * q;
                const unsigned kd2 = *(const unsigned*)(&sKD[c * 18 + jj]);
                const unsigned vg2 = *(const unsigned*)(&sGV[0 * 2304 + c * 18 + jj]);
                const unsigned p12 = *(const unsigned*)(&sGV[1 * 2304 + c * 18 + jj]);
                const unsigned p22 = *(const unsigned*)(&sGV[2 * 2304 + c * 18 + jj]);
                const float cut0 = sCut[jj];
                const float cut1 = sCut[jj + 1];
                const float p0 = __expf(qsc * bflo(kd2));
                const float p1 = __expf(qsc * bfhi(kd2));
                l += p0 + p1;
                A = fmaf(p0 * cut0, bflo(vg2), A);
                A = fmaf(p1 * cut1, bfhi(vg2), A);
                if (cut0 != 0.0f) {
                    const unsigned short* vp = svel + (size_t)jj * 384 + c;
                    const float w1 = bflo(p12), w2 = bflo(p22);
                    v0 = fmaf(bfu(vp[0]),   w1, fmaf(w2, sDirS[jj * 3 + 0], v0));
                    v1 = fmaf(bfu(vp[128]), w1, fmaf(w2, sDirS[jj * 3 + 1], v1));
                    v2 = fmaf(bfu(vp[256]), w1, fmaf(w2, sDirS[jj * 3 + 2], v2));
                }
                if (cut1 != 0.0f) {
                    const unsigned short* vp = svel + (size_t)(jj + 1) * 384 + c;
                    const float w1 = bfhi(p12), w2 = bfhi(p22);
                    v0 = fmaf(bfu(vp[0]),   w1, fmaf(w2, sDirS[jj * 3 + 3], v0));
                    v1 = fmaf(bfu(vp[128]), w1, fmaf(w2, sDirS[jj * 3 + 4], v1));
                    v2 = fmaf(bfu(vp[256]), w1, fmaf(w2, sDirS[jj * 3 + 5], v2));
                }
            }
        }
        __syncthreads();   // C: vel(t) dead; gate-stage(t+1) drained

        // ---- issue vel-stage(t+1) (overlaps EF-write; drains at next A) ----
        if (j0 + TJ < TT) {
            const unsigned char* src = kvT + (size_t)((j0 >> 4) + 1) * SRCB;
#pragma unroll
            for (int r = 4; r < 7; ++r)
                __builtin_amdgcn_global_load_lds(
                    (const void*)(src + (size_t)r * 4096 + (size_t)t * 16),
                    (void*)(sSrc + r * 4096 + ldsoff), 16, 0, 0);
        }
    }

    // merge the two j-groups
    if (grp == 1) {
        sMrg[c][0] = l;  sMrg[c][1] = A;
        sMrg[c][2] = v0; sMrg[c][3] = v1; sMrg[c][4] = v2;
    }
    __syncthreads();
    if (grp == 0) {
        const float L = l + sMrg[c][0];
        const float Aa = A + sMrg[c][1];
        const float attn = (L > 0.f) ? (Aa * __builtin_amdgcn_rcpf(L)) : 0.f;
        attn_ws[(size_t)row * 128 + c] = attn;
        vec_ws[((size_t)row * 3 + 0) * 128 + c] = v0 + sMrg[c][2];
        vec_ws[((size_t)row * 3 + 1) * 128 + c] = v1 + sMrg[c][3];
        vec_ws[((size_t)row * 3 + 2) * 128 + c] = v2 + sMrg[c][4];
    }
}

// ---------------- Phase C: output projection + epilogue ----------------
__global__ __launch_bounds__(256) void phaseC_kernel(
    const float* __restrict__ Wo, const float* __restrict__ bo,
    const float* __restrict__ attn_ws, const float* __restrict__ veldot_ws,
    const float* __restrict__ w3_ws, const float* __restrict__ vec_ws,
    float* __restrict__ out) {
    const int row = blockIdx.x;
    const int t = threadIdx.x;
    __shared__ float sAttn[128];
    __shared__ float sO[384];
    if (t < 128) sAttn[t] = attn_ws[(size_t)row * 128 + t];
    __syncthreads();
    for (int o = t; o < 384; o += 256) {
        float acc = bo[o];
#pragma unroll 8
        for (int r = 0; r < 128; ++r) acc = fmaf(sAttn[r], Wo[r * 384 + o], acc);
        sO[o] = acc;
    }
    __syncthreads();
    if (t < 128) {
        int c = t;
        float o1 = sO[c], o2 = sO[128 + c], o3 = sO[256 + c];
        float dx = fmaf(veldot_ws[(size_t)row * 128 + c], o2, o3);
        out[(size_t)row * 128 + c] = dx;
#pragma unroll
        for (int s = 0; s < 3; ++s) {
            size_t idx = ((size_t)row * 3 + s) * 128 + c;
            out[131072 + idx] = fmaf(w3_ws[idx], o1, vec_ws[idx]);
        }
    }
}

extern "C" void kernel_launch(void* const* d_in, const int* in_sizes, int n_in,
                              void* d_out, int out_size, void* d_ws, size_t ws_size,
                              hipStream_t stream) {
    (void)in_sizes; (void)n_in; (void)out_size; (void)ws_size;
    const float* query          = (const float*)d_in[0];
    const float* velocity       = (const float*)d_in[1];
    const float* edge_feature   = (const float*)d_in[2];
    const float* edge_direction = (const float*)d_in[3];
    const float* cutoff         = (const float*)d_in[4];
    const float* Wq   = (const float*)d_in[5];  const float* bq   = (const float*)d_in[6];
    const float* Wk   = (const float*)d_in[7];  const float* bk   = (const float*)d_in[8];
    const float* Wv   = (const float*)d_in[9];  const float* bv   = (const float*)d_in[10];
    const float* Wo   = (const float*)d_in[11]; const float* bo   = (const float*)d_in[12];
    const float* Wvel = (const float*)d_in[13]; const float* bvel = (const float*)d_in[14];
    const float* Wdk  = (const float*)d_in[15]; const float* bdk  = (const float*)d_in[16];
    const float* Wdv  = (const float*)d_in[17]; const float* bdv  = (const float*)d_in[18];

    float* ws        = (float*)d_ws;
    float* qs_ws     = ws;              // 131072
    float* veldot_ws = ws + 131072;     // 131072
    float* w3_ws     = ws + 262144;     // 393216
    float* attn_ws   = ws + 655360;     // 131072
    float* vec_ws    = ws + 786432;     // 393216
    unsigned short* wfrag = (unsigned short*)(ws + 1179648);  // 32768 shorts
    unsigned short* kkvvT = (unsigned short*)(ws + 1196032);  // 64 tiles * 14336 shorts

    float* out = (float*)d_out;

    hipLaunchKernelGGL(packW_kernel, dim3(16), dim3(256), 0, stream,
        Wdk, Wdv, wfrag);
    hipLaunchKernelGGL(phaseA_kernel, dim3(1024), dim3(256), 0, stream,
        query, velocity, Wq, bq, Wk, bk, Wv, bv, Wvel, bvel,
        qs_ws, kkvvT, veldot_ws, w3_ws);
    hipLaunchKernelGGL(phaseB_kernel, dim3(1024), dim3(256), 0, stream,
        edge_feature, edge_direction, cutoff,
        wfrag, kkvvT, bdk, bdv, qs_ws, attn_ws, vec_ws);
    hipLaunchKernelGGL(phaseC_kernel, dim3(1024), dim3(256), 0, stream,
        Wo, bo, attn_ws, veldot_ws, w3_ws, vec_ws, out);
}